// Round 1
// baseline (118.157 us; speedup 1.0000x reference)
//
#include <hip/hip_runtime.h>
#include <hip/hip_bf16.h>
#include <math.h>

// S4D joint kernel generation:
//   Ku[h,l]     = 2*Re( sum_n C_main[h,n]  * exp(dtA[h,n]*l) )
//   Kx[h,l]     = 2*Re( sum_n E_main[h,n]  * exp(dtA[h,n]*l) )
//   Ku_aux[h,l] = 2*Re( sum_n C_aux_d[h,n] * exp(dtA[h,n]*l) )
//   Kx_aux[h,l] = 2*Re( sum_n E_aux[h,n]   * exp(dtA[h,n]*l) )
// Strategy: block = (h, chunk of 2048 l). 256 threads, each owns U=8
// consecutive l. Per-h mode coefficients computed once (f64) into LDS.
// Inner loop: per mode n, anchor exp(dtA*l0) via 1 exp + 1 sincos with
// f64 mod-2pi angle reduction (f32 angle at l~4096, |im|~10 would lose
// ~5e-3 rad), then rotate by step=exp(dtA) per l (2 mul + 2 fma).

#define U 8
#define NMAX 64

__global__ __launch_bounds__(256) void s4d_joint_kernel(
    const float* __restrict__ C_r,
    const float* __restrict__ Ca_r,
    const float* __restrict__ E_r,
    const float* __restrict__ log_dt,
    const float* __restrict__ log_A_real,
    const float* __restrict__ A_imag,
    float* __restrict__ out,
    int H, int N2, int L)
{
    const int h = blockIdx.y;
    const int tid = threadIdx.x;

    // Per-mode staged coefficients (broadcast-read from LDS).
    __shared__ float  s_dre[NMAX];               // Re(dtA)  (anchor exp arg per l)
    __shared__ double s_dimd[NMAX];              // Im(dtA) in f64 (anchor angle)
    __shared__ float  s_pr[NMAX], s_pi[NMAX];    // step = exp(dtA)
    __shared__ float  s_cmr[NMAX], s_cmi[NMAX];  // 2*C_main
    __shared__ float  s_car[NMAX], s_cai[NMAX];  // 2*C_aux_d
    __shared__ float  s_emr[NMAX], s_emi[NMAX];  // 2*E_main
    __shared__ float  s_ear[NMAX], s_eai[NMAX];  // 2*E_aux

    if (tid < N2) {
        const int n = tid;
        const double ldt = (double)log_dt[h];
        const double dtd = exp(ldt);
        const double are = -exp((double)log_A_real[h * N2 + n]);
        const double aim = (double)A_imag[h * N2 + n];
        const double dre = are * dtd;
        const double dim = aim * dtd;
        // exp(dtA)
        const double er  = exp(dre);
        const double Ere = er * cos(dim);
        const double Eim = er * sin(dim);
        // scale = (exp(dtA)-1)/A
        const double den = are * are + aim * aim;
        const double nr  = Ere - 1.0, ni = Eim;
        const double scr = (nr * are + ni * aim) / den;
        const double sci = (ni * are - nr * aim) / den;
        // C_main = C*scale ; C_aux_d = C_aux*scale
        const double cr  = (double)C_r [(h * N2 + n) * 2 + 0];
        const double ci  = (double)C_r [(h * N2 + n) * 2 + 1];
        const double ar  = (double)Ca_r[(h * N2 + n) * 2 + 0];
        const double ai  = (double)Ca_r[(h * N2 + n) * 2 + 1];
        const double exr = (double)E_r [(h * N2 + n) * 2 + 0];
        const double exi = (double)E_r [(h * N2 + n) * 2 + 1];
        const double cmr = cr * scr - ci * sci;
        const double cmi = cr * sci + ci * scr;
        const double car = ar * scr - ai * sci;
        const double cai = ar * sci + ai * scr;
        // E_main = E*C_main ; E_aux = E*C_aux_d
        const double emr = exr * cmr - exi * cmi;
        const double emi = exr * cmi + exi * cmr;
        const double ear = exr * car - exi * cai;
        const double eai = exr * cai + exi * car;

        s_dre[n]  = (float)dre;
        s_dimd[n] = dim;
        s_pr[n]   = (float)Ere;
        s_pi[n]   = (float)Eim;
        s_cmr[n]  = (float)(2.0 * cmr);
        s_cmi[n]  = (float)(2.0 * cmi);
        s_car[n]  = (float)(2.0 * car);
        s_cai[n]  = (float)(2.0 * cai);
        s_emr[n]  = (float)(2.0 * emr);
        s_emi[n]  = (float)(2.0 * emi);
        s_ear[n]  = (float)(2.0 * ear);
        s_eai[n]  = (float)(2.0 * eai);
    }
    __syncthreads();

    const int l0 = blockIdx.x * (256 * U) + tid * U;
    if (l0 >= L) return;

    float accKu[U], accKx[U], accKua[U], accKxa[U];
#pragma unroll
    for (int j = 0; j < U; ++j) { accKu[j] = 0.f; accKx[j] = 0.f; accKua[j] = 0.f; accKxa[j] = 0.f; }

    const float l0f = (float)l0;

    for (int n = 0; n < N2; ++n) {
        const float dre = s_dre[n];
        const float pr  = s_pr[n],  pi  = s_pi[n];
        const float cmr = s_cmr[n], cmi = s_cmi[n];
        const float car = s_car[n], cai = s_cai[n];
        const float emr = s_emr[n], emi = s_emi[n];
        const float ear = s_ear[n], eai = s_eai[n];

        // Anchor: exp(dtA * l0), angle reduced mod 2pi in f64.
        double t = s_dimd[n] * (double)l0 * 0.15915494309189535; // /(2pi)
        t -= rint(t);
        const float ang = (float)t * 6.28318530717958648f;
        float sn, cs;
        __sincosf(ang, &sn, &cs);
        const float er = __expf(dre * l0f);
        float exr = er * cs;
        float exi = er * sn;

#pragma unroll
        for (int j = 0; j < U; ++j) {
            accKu[j]  = fmaf(cmr, exr, fmaf(-cmi, exi, accKu[j]));
            accKx[j]  = fmaf(emr, exr, fmaf(-emi, exi, accKx[j]));
            accKua[j] = fmaf(car, exr, fmaf(-cai, exi, accKua[j]));
            accKxa[j] = fmaf(ear, exr, fmaf(-eai, exi, accKxa[j]));
            // rotate: ex *= step
            const float nrr = fmaf(exr, pr, -(exi * pi));
            const float nii = fmaf(exr, pi,  (exi * pr));
            exr = nrr; exi = nii;
        }
    }

    const size_t HL   = (size_t)H * (size_t)L;
    const size_t base = (size_t)h * (size_t)L + (size_t)l0;
    if (l0 + U <= L) {
        float4* o0 = reinterpret_cast<float4*>(out + base);
        float4* o1 = reinterpret_cast<float4*>(out + HL + base);
        float4* o2 = reinterpret_cast<float4*>(out + 2 * HL + base);
        float4* o3 = reinterpret_cast<float4*>(out + 3 * HL + base);
        o0[0] = make_float4(accKu[0],  accKu[1],  accKu[2],  accKu[3]);
        o0[1] = make_float4(accKu[4],  accKu[5],  accKu[6],  accKu[7]);
        o1[0] = make_float4(accKx[0],  accKx[1],  accKx[2],  accKx[3]);
        o1[1] = make_float4(accKx[4],  accKx[5],  accKx[6],  accKx[7]);
        o2[0] = make_float4(accKua[0], accKua[1], accKua[2], accKua[3]);
        o2[1] = make_float4(accKua[4], accKua[5], accKua[6], accKua[7]);
        o3[0] = make_float4(accKxa[0], accKxa[1], accKxa[2], accKxa[3]);
        o3[1] = make_float4(accKxa[4], accKxa[5], accKxa[6], accKxa[7]);
    } else {
        for (int j = 0; j < U && l0 + j < L; ++j) {
            out[base + j]          = accKu[j];
            out[HL + base + j]     = accKx[j];
            out[2 * HL + base + j] = accKua[j];
            out[3 * HL + base + j] = accKxa[j];
        }
    }
}

extern "C" void kernel_launch(void* const* d_in, const int* in_sizes, int n_in,
                              void* d_out, int out_size, void* d_ws, size_t ws_size,
                              hipStream_t stream) {
    const float* C_r        = (const float*)d_in[0];
    const float* Ca_r       = (const float*)d_in[1];
    const float* E_r        = (const float*)d_in[2];
    const float* log_dt     = (const float*)d_in[3];
    const float* log_A_real = (const float*)d_in[4];
    const float* A_imag     = (const float*)d_in[5];
    float* out = (float*)d_out;

    const int H  = in_sizes[3];
    const int N2 = in_sizes[4] / H;
    const int L  = out_size / (4 * H);

    const int lpb = 256 * U;
    dim3 grid((L + lpb - 1) / lpb, H);
    dim3 block(256);
    s4d_joint_kernel<<<grid, block, 0, stream>>>(
        C_r, Ca_r, E_r, log_dt, log_A_real, A_imag, out, H, N2, L);
}

// Round 3
// 115.767 us; speedup vs baseline: 1.0206x; 1.0206x over previous
//
#include <hip/hip_runtime.h>
#include <hip/hip_bf16.h>
#include <math.h>

// S4D joint kernel generation, packed-f32 version.
//   out[k][h,l] = 2*Re( sum_n coef_k[h,n] * exp(dtA[h,n]*l) ),  k=0..3
// Per (n,l): 4x v_pk_fma_f32 (accum, coef packed (2cr,-2ci)) +
//            2x packed rotation via op_sel broadcast = 6 VALU instrs
// (was 12 scalar). Anchor per (n,thread): f64 mod-2pi angle + __sincosf/__expf.

#define U 8
#define NMAX 64

typedef float f32x2 __attribute__((ext_vector_type(2)));

__device__ __forceinline__ f32x2 pk_fma(f32x2 a, f32x2 b, f32x2 c) {
    f32x2 d;
    asm("v_pk_fma_f32 %0, %1, %2, %3" : "=v"(d) : "v"(a), "v"(b), "v"(c));
    return d;
}

// ex' = ex * (pr + i*pi), with sa=(pr,pi), sb=(-pi,pr).
// t  = (exi*-pi, exi*pr)           [src0 broadcast hi]
// ex'= (exr*pr + t.lo, exr*pi + t.hi) [src0 broadcast lo]
__device__ __forceinline__ f32x2 rot_step(f32x2 ex, f32x2 sa, f32x2 sb) {
    f32x2 t, r;
    asm("v_pk_mul_f32 %0, %1, %2 op_sel:[1,0] op_sel_hi:[1,1]"
        : "=v"(t) : "v"(ex), "v"(sb));
    asm("v_pk_fma_f32 %0, %1, %2, %3 op_sel:[0,0,0] op_sel_hi:[0,1,1]"
        : "=v"(r) : "v"(ex), "v"(sa), "v"(t));
    return r;
}

__global__ __launch_bounds__(256) void s4d_joint_kernel(
    const float* __restrict__ C_r,
    const float* __restrict__ Ca_r,
    const float* __restrict__ E_r,
    const float* __restrict__ log_dt,
    const float* __restrict__ log_A_real,
    const float* __restrict__ A_imag,
    float* __restrict__ out,
    int H, int N2, int L)
{
    const int h = blockIdx.y;
    const int tid = threadIdx.x;

    __shared__ f32x2  s_sa[NMAX];   // step = exp(dtA) = (pr, pi)
    __shared__ f32x2  s_sb[NMAX];   // (-pi, pr)
    __shared__ f32x2  s_cm[NMAX];   // (2*cmr, -2*cmi)
    __shared__ f32x2  s_em[NMAX];
    __shared__ f32x2  s_ca[NMAX];
    __shared__ f32x2  s_ea[NMAX];
    __shared__ float  s_dre[NMAX];  // Re(dtA)
    __shared__ double s_dim[NMAX];  // Im(dtA) in f64

    if (tid < N2) {
        const int n = tid;
        const double dtd = exp((double)log_dt[h]);
        const double are = -exp((double)log_A_real[h * N2 + n]);
        const double aim = (double)A_imag[h * N2 + n];
        const double dre = are * dtd;
        const double dim = aim * dtd;
        const double er  = exp(dre);
        const double Ere = er * cos(dim);
        const double Eim = er * sin(dim);
        const double den = are * are + aim * aim;
        const double nr  = Ere - 1.0, ni = Eim;
        const double scr = (nr * are + ni * aim) / den;
        const double sci = (ni * are - nr * aim) / den;
        const double cr  = (double)C_r [(h * N2 + n) * 2 + 0];
        const double ci  = (double)C_r [(h * N2 + n) * 2 + 1];
        const double ar  = (double)Ca_r[(h * N2 + n) * 2 + 0];
        const double ai  = (double)Ca_r[(h * N2 + n) * 2 + 1];
        const double exr = (double)E_r [(h * N2 + n) * 2 + 0];
        const double exi = (double)E_r [(h * N2 + n) * 2 + 1];
        const double cmr = cr * scr - ci * sci;
        const double cmi = cr * sci + ci * scr;
        const double car = ar * scr - ai * sci;
        const double cai = ar * sci + ai * scr;
        const double emr = exr * cmr - exi * cmi;
        const double emi = exr * cmi + exi * cmr;
        const double ear = exr * car - exi * cai;
        const double eai = exr * cai + exi * car;

        f32x2 v;
        v.x = (float)Ere;          v.y = (float)Eim;          s_sa[n] = v;
        v.x = (float)(-Eim);       v.y = (float)Ere;          s_sb[n] = v;
        v.x = (float)(2.0 * cmr);  v.y = (float)(-2.0 * cmi); s_cm[n] = v;
        v.x = (float)(2.0 * emr);  v.y = (float)(-2.0 * emi); s_em[n] = v;
        v.x = (float)(2.0 * car);  v.y = (float)(-2.0 * cai); s_ca[n] = v;
        v.x = (float)(2.0 * ear);  v.y = (float)(-2.0 * eai); s_ea[n] = v;
        s_dre[n] = (float)dre;
        s_dim[n] = dim;
    }
    __syncthreads();

    const int l0 = blockIdx.x * (256 * U) + tid * U;
    if (l0 >= L) return;
    const float l0f = (float)l0;

    f32x2 accU[U], accX[U], accUa[U], accXa[U];
#pragma unroll
    for (int j = 0; j < U; ++j) {
        accU[j]  = (f32x2)0.f; accX[j]  = (f32x2)0.f;
        accUa[j] = (f32x2)0.f; accXa[j] = (f32x2)0.f;
    }

    for (int n = 0; n < N2; ++n) {
        const f32x2 sa = s_sa[n], sb = s_sb[n];
        const f32x2 cm = s_cm[n], em = s_em[n];
        const f32x2 ca = s_ca[n], ea = s_ea[n];

        // Anchor exp(dtA*l0): f64 mod-2pi angle reduction.
        double t = s_dim[n] * (double)l0 * 0.15915494309189535;
        t -= rint(t);
        const float ang = (float)t * 6.28318530717958648f;
        float sn, cs;
        __sincosf(ang, &sn, &cs);
        const float er = __expf(s_dre[n] * l0f);
        f32x2 ex; ex.x = er * cs; ex.y = er * sn;

#pragma unroll
        for (int j = 0; j < U; ++j) {
            accU[j]  = pk_fma(cm, ex, accU[j]);
            accX[j]  = pk_fma(em, ex, accX[j]);
            accUa[j] = pk_fma(ca, ex, accUa[j]);
            accXa[j] = pk_fma(ea, ex, accXa[j]);
            if (j < U - 1) ex = rot_step(ex, sa, sb);
        }
    }

    const size_t HL   = (size_t)H * (size_t)L;
    const size_t base = (size_t)h * (size_t)L + (size_t)l0;
    if (l0 + U <= L) {
        float4* o0 = reinterpret_cast<float4*>(out + base);
        float4* o1 = reinterpret_cast<float4*>(out + HL + base);
        float4* o2 = reinterpret_cast<float4*>(out + 2 * HL + base);
        float4* o3 = reinterpret_cast<float4*>(out + 3 * HL + base);
        o0[0] = make_float4(accU[0].x + accU[0].y,  accU[1].x + accU[1].y,
                            accU[2].x + accU[2].y,  accU[3].x + accU[3].y);
        o0[1] = make_float4(accU[4].x + accU[4].y,  accU[5].x + accU[5].y,
                            accU[6].x + accU[6].y,  accU[7].x + accU[7].y);
        o1[0] = make_float4(accX[0].x + accX[0].y,  accX[1].x + accX[1].y,
                            accX[2].x + accX[2].y,  accX[3].x + accX[3].y);
        o1[1] = make_float4(accX[4].x + accX[4].y,  accX[5].x + accX[5].y,
                            accX[6].x + accX[6].y,  accX[7].x + accX[7].y);
        o2[0] = make_float4(accUa[0].x + accUa[0].y, accUa[1].x + accUa[1].y,
                            accUa[2].x + accUa[2].y, accUa[3].x + accUa[3].y);
        o2[1] = make_float4(accUa[4].x + accUa[4].y, accUa[5].x + accUa[5].y,
                            accUa[6].x + accUa[6].y, accUa[7].x + accUa[7].y);
        o3[0] = make_float4(accXa[0].x + accXa[0].y, accXa[1].x + accXa[1].y,
                            accXa[2].x + accXa[2].y, accXa[3].x + accXa[3].y);
        o3[1] = make_float4(accXa[4].x + accXa[4].y, accXa[5].x + accXa[5].y,
                            accXa[6].x + accXa[6].y, accXa[7].x + accXa[7].y);
    } else {
        for (int j = 0; j < U && l0 + j < L; ++j) {
            out[base + j]          = accU[j].x  + accU[j].y;
            out[HL + base + j]     = accX[j].x  + accX[j].y;
            out[2 * HL + base + j] = accUa[j].x + accUa[j].y;
            out[3 * HL + base + j] = accXa[j].x + accXa[j].y;
        }
    }
}

extern "C" void kernel_launch(void* const* d_in, const int* in_sizes, int n_in,
                              void* d_out, int out_size, void* d_ws, size_t ws_size,
                              hipStream_t stream) {
    const float* C_r        = (const float*)d_in[0];
    const float* Ca_r       = (const float*)d_in[1];
    const float* E_r        = (const float*)d_in[2];
    const float* log_dt     = (const float*)d_in[3];
    const float* log_A_real = (const float*)d_in[4];
    const float* A_imag     = (const float*)d_in[5];
    float* out = (float*)d_out;

    const int H  = in_sizes[3];
    const int N2 = in_sizes[4] / H;
    const int L  = out_size / (4 * H);

    const int lpb = 256 * U;
    dim3 grid((L + lpb - 1) / lpb, H);
    dim3 block(256);
    s4d_joint_kernel<<<grid, block, 0, stream>>>(
        C_r, Ca_r, E_r, log_dt, log_A_real, A_imag, out, H, N2, L);
}

// Round 4
// 115.506 us; speedup vs baseline: 1.0229x; 1.0023x over previous
//
#include <hip/hip_runtime.h>
#include <hip/hip_bf16.h>
#include <math.h>

// S4D joint kernel, l-packed VOP3P version.
//   out[k][h,l] = 2*Re( sum_n coef_k[h,n] * exp(dtA[h,n]*l) ),  k=0..3
// One block per h; 256 threads x U=16 consecutive l each (covers L=4096).
// State per mode n: ex_r=(e(l),e(l+1)).re, ex_i=...im ; rotate pairs by R=r^2.
// Per l-pair: 8 pk_fma accum (4 outputs x 2) + 4 pk rot = 12 instrs = 6/l.
// Anchor per (n,thread): f64 mod-2pi angle + __sincosf/__expf, amortized /16.

#define U 16
#define NMAX 64

typedef float f32x2 __attribute__((ext_vector_type(2)));

// d = broadcast_lo(a) * b + c
__device__ __forceinline__ f32x2 pk_fma_blo(f32x2 a, f32x2 b, f32x2 c) {
    f32x2 d;
    asm("v_pk_fma_f32 %0, %1, %2, %3 op_sel:[0,0,0] op_sel_hi:[0,1,1]"
        : "=v"(d) : "v"(a), "v"(b), "v"(c));
    return d;
}
// d = broadcast_hi(a) * b + c
__device__ __forceinline__ f32x2 pk_fma_bhi(f32x2 a, f32x2 b, f32x2 c) {
    f32x2 d;
    asm("v_pk_fma_f32 %0, %1, %2, %3 op_sel:[1,0,0] op_sel_hi:[1,1,1]"
        : "=v"(d) : "v"(a), "v"(b), "v"(c));
    return d;
}
// d = broadcast_lo(a) * b
__device__ __forceinline__ f32x2 pk_mul_blo(f32x2 a, f32x2 b) {
    f32x2 d;
    asm("v_pk_mul_f32 %0, %1, %2 op_sel:[0,0] op_sel_hi:[0,1]"
        : "=v"(d) : "v"(a), "v"(b));
    return d;
}
// d = broadcast_hi(a) * b
__device__ __forceinline__ f32x2 pk_mul_bhi(f32x2 a, f32x2 b) {
    f32x2 d;
    asm("v_pk_mul_f32 %0, %1, %2 op_sel:[1,0] op_sel_hi:[1,1]"
        : "=v"(d) : "v"(a), "v"(b));
    return d;
}

__global__ __launch_bounds__(256) void s4d_joint_kernel(
    const float* __restrict__ C_r,
    const float* __restrict__ Ca_r,
    const float* __restrict__ E_r,
    const float* __restrict__ log_dt,
    const float* __restrict__ log_A_real,
    const float* __restrict__ A_imag,
    float* __restrict__ out,
    int H, int N2, int L)
{
    const int h = blockIdx.y;
    const int tid = threadIdx.x;

    __shared__ f32x2  s_cm[NMAX], s_em[NMAX], s_ca[NMAX], s_ea[NMAX]; // (2cr,-2ci)
    __shared__ f32x2  s_Ra[NMAX];   // R=r^2: (Rr, Ri)
    __shared__ f32x2  s_Rb[NMAX];   // (Rr, -Ri)
    __shared__ f32x2  s_r [NMAX];   // r = exp(dtA) = (pr, pi)
    __shared__ float  s_dre[NMAX];  // Re(dtA)
    __shared__ double s_dim[NMAX];  // Im(dtA)/(2pi) in f64

    if (tid < N2) {
        const int n = tid;
        const double dtd = exp((double)log_dt[h]);
        const double are = -exp((double)log_A_real[h * N2 + n]);
        const double aim = (double)A_imag[h * N2 + n];
        const double dre = are * dtd;
        const double dim = aim * dtd;
        const double er  = exp(dre);
        const double Ere = er * cos(dim);
        const double Eim = er * sin(dim);
        const double den = are * are + aim * aim;
        const double nr  = Ere - 1.0, ni = Eim;
        const double scr = (nr * are + ni * aim) / den;
        const double sci = (ni * are - nr * aim) / den;
        const double cr  = (double)C_r [(h * N2 + n) * 2 + 0];
        const double ci  = (double)C_r [(h * N2 + n) * 2 + 1];
        const double ar  = (double)Ca_r[(h * N2 + n) * 2 + 0];
        const double ai  = (double)Ca_r[(h * N2 + n) * 2 + 1];
        const double exr = (double)E_r [(h * N2 + n) * 2 + 0];
        const double exi = (double)E_r [(h * N2 + n) * 2 + 1];
        const double cmr = cr * scr - ci * sci;
        const double cmi = cr * sci + ci * scr;
        const double car = ar * scr - ai * sci;
        const double cai = ar * sci + ai * scr;
        const double emr = exr * cmr - exi * cmi;
        const double emi = exr * cmi + exi * cmr;
        const double ear = exr * car - exi * cai;
        const double eai = exr * cai + exi * car;
        const double Rr  = Ere * Ere - Eim * Eim;  // r^2
        const double Ri  = 2.0 * Ere * Eim;

        f32x2 v;
        v.x = (float)(2.0 * cmr);  v.y = (float)(-2.0 * cmi); s_cm[n] = v;
        v.x = (float)(2.0 * emr);  v.y = (float)(-2.0 * emi); s_em[n] = v;
        v.x = (float)(2.0 * car);  v.y = (float)(-2.0 * cai); s_ca[n] = v;
        v.x = (float)(2.0 * ear);  v.y = (float)(-2.0 * eai); s_ea[n] = v;
        v.x = (float)Rr;           v.y = (float)Ri;           s_Ra[n] = v;
        v.x = (float)Rr;           v.y = (float)(-Ri);        s_Rb[n] = v;
        v.x = (float)Ere;          v.y = (float)Eim;          s_r[n]  = v;
        s_dre[n] = (float)dre;
        s_dim[n] = dim * 0.15915494309189535;  // /(2pi)
    }
    __syncthreads();

    const int l0 = blockIdx.x * (256 * U) + tid * U;
    if (l0 >= L) return;
    const float  lbf = (float)l0;
    const double lbd = (double)l0;

    f32x2 aU[U/2], aX[U/2], aUa[U/2], aXa[U/2];
#pragma unroll
    for (int p = 0; p < U/2; ++p) {
        aU[p]  = (f32x2)0.f; aX[p]  = (f32x2)0.f;
        aUa[p] = (f32x2)0.f; aXa[p] = (f32x2)0.f;
    }

#pragma unroll 2
    for (int n = 0; n < N2; ++n) {
        const f32x2 cm = s_cm[n], em = s_em[n], ca = s_ca[n], ea = s_ea[n];
        const f32x2 Ra = s_Ra[n], Rb = s_Rb[n], rr = s_r[n];

        // Anchor e0 = exp(dtA*l0), e1 = e0*r ; f64 mod-2pi angle reduction.
        double t = s_dim[n] * lbd;
        t -= rint(t);
        const float ang = (float)t * 6.28318530717958648f;
        float sn, cs;
        __sincosf(ang, &sn, &cs);
        const float er  = __expf(s_dre[n] * lbf);
        const float e0r = er * cs, e0i = er * sn;
        const float e1r = fmaf(e0r, rr.x, -(e0i * rr.y));
        const float e1i = fmaf(e0r, rr.y,  (e0i * rr.x));
        f32x2 exr, exi;
        exr.x = e0r; exr.y = e1r;
        exi.x = e0i; exi.y = e1i;

#pragma unroll
        for (int p = 0; p < U/2; ++p) {
            aU[p]  = pk_fma_blo(cm, exr, aU[p]);
            aU[p]  = pk_fma_bhi(cm, exi, aU[p]);
            aX[p]  = pk_fma_blo(em, exr, aX[p]);
            aX[p]  = pk_fma_bhi(em, exi, aX[p]);
            aUa[p] = pk_fma_blo(ca, exr, aUa[p]);
            aUa[p] = pk_fma_bhi(ca, exi, aUa[p]);
            aXa[p] = pk_fma_blo(ea, exr, aXa[p]);
            aXa[p] = pk_fma_bhi(ea, exi, aXa[p]);
            if (p < U/2 - 1) {
                const f32x2 t1 = pk_mul_blo(Ra, exr);   // (Rr*xr0, Rr*xr1)
                const f32x2 t2 = pk_mul_bhi(Ra, exr);   // (Ri*xr0, Ri*xr1)
                exr = pk_fma_bhi(Rb, exi, t1);          // Rr*xr - Ri*xi
                exi = pk_fma_blo(Ra, exi, t2);          // Rr*xi + Ri*xr
            }
        }
    }

    const size_t HL   = (size_t)H * (size_t)L;
    const size_t base = (size_t)h * (size_t)L + (size_t)l0;
    if (l0 + U <= L) {
        float4* o0 = reinterpret_cast<float4*>(out + base);
        float4* o1 = reinterpret_cast<float4*>(out + HL + base);
        float4* o2 = reinterpret_cast<float4*>(out + 2 * HL + base);
        float4* o3 = reinterpret_cast<float4*>(out + 3 * HL + base);
#pragma unroll
        for (int q = 0; q < U/4; ++q) {
            o0[q] = make_float4(aU[2*q].x,  aU[2*q].y,  aU[2*q+1].x,  aU[2*q+1].y);
            o1[q] = make_float4(aX[2*q].x,  aX[2*q].y,  aX[2*q+1].x,  aX[2*q+1].y);
            o2[q] = make_float4(aUa[2*q].x, aUa[2*q].y, aUa[2*q+1].x, aUa[2*q+1].y);
            o3[q] = make_float4(aXa[2*q].x, aXa[2*q].y, aXa[2*q+1].x, aXa[2*q+1].y);
        }
    } else {
        for (int j = 0; j < U && l0 + j < L; ++j) {
            const int p = j >> 1;
            const float vU  = (j & 1) ? aU[p].y  : aU[p].x;
            const float vX  = (j & 1) ? aX[p].y  : aX[p].x;
            const float vUa = (j & 1) ? aUa[p].y : aUa[p].x;
            const float vXa = (j & 1) ? aXa[p].y : aXa[p].x;
            out[base + j]          = vU;
            out[HL + base + j]     = vX;
            out[2 * HL + base + j] = vUa;
            out[3 * HL + base + j] = vXa;
        }
    }
}

extern "C" void kernel_launch(void* const* d_in, const int* in_sizes, int n_in,
                              void* d_out, int out_size, void* d_ws, size_t ws_size,
                              hipStream_t stream) {
    const float* C_r        = (const float*)d_in[0];
    const float* Ca_r       = (const float*)d_in[1];
    const float* E_r        = (const float*)d_in[2];
    const float* log_dt     = (const float*)d_in[3];
    const float* log_A_real = (const float*)d_in[4];
    const float* A_imag     = (const float*)d_in[5];
    float* out = (float*)d_out;

    const int H  = in_sizes[3];
    const int N2 = in_sizes[4] / H;
    const int L  = out_size / (4 * H);

    const int lpb = 256 * U;
    dim3 grid((L + lpb - 1) / lpb, H);
    dim3 block(256);
    s4d_joint_kernel<<<grid, block, 0, stream>>>(
        C_r, Ca_r, E_r, log_dt, log_A_real, A_imag, out, H, N2, L);
}